// Round 7
// baseline (143.406 us; speedup 1.0000x reference)
//
#include <hip/hip_runtime.h>

typedef __attribute__((ext_vector_type(4))) float f32x4;
typedef __attribute__((ext_vector_type(4))) int   i32x4;
typedef __attribute__((ext_vector_type(8))) int   i32x8;

#define DIM 256
#define D4  64    // float4 per row

// async global->LDS, 16B per lane; LDS dest = wave-uniform base + lane*16.
#define GLD_LDS16(g, l) __builtin_amdgcn_global_load_lds(                      \
    (const __attribute__((address_space(1))) void*)(g),                        \
    (__attribute__((address_space(3))) void*)(l), 16, 0, 0)

// wait for all but the newest N VMEM ops, then barrier (counted prefetch).
#define TILE_WAIT(N) asm volatile("s_waitcnt vmcnt(" #N ")\n\ts_barrier" ::: "memory")

// One wave per row. Rows [0,N): exact fp32 pos_sim -> posPart[row] + normalized
// pk -> fp8 e4m3. Rows [N,N+M): normalized nv -> fp8. R13: block 0 also zeroes
// `out` and the 32 per-panel completion counters (replaces the hipMemsetAsync
// dispatch; visibility to the gemm dispatch is the same-stream inter-kernel
// guarantee we already rely on for pkn/nvn).
__global__ __launch_bounds__(256) void normalize_kernel(
    const float4* __restrict__ pk, const float4* __restrict__ pv,
    const float4* __restrict__ nv, unsigned int* __restrict__ pkn,
    unsigned int* __restrict__ nvn, float* __restrict__ posPart,
    int* __restrict__ ctr, float* __restrict__ out, int N) {
  if (blockIdx.x == 0) {
    int t = threadIdx.x;
    if (t < 32) ctr[t] = 0;
    if (t == 32) out[0] = 0.f;
  }
  int row  = blockIdx.x * 4 + (threadIdx.x >> 6);
  int lane = threadIdx.x & 63;
  if (row < N) {
    float4 x = pk[row * D4 + lane];
    float4 y = pv[row * D4 + lane];
    float skk = x.x*x.x + x.y*x.y + x.z*x.z + x.w*x.w;
    float svv = y.x*y.x + y.y*y.y + y.z*y.z + y.w*y.w;
    float skv = x.x*y.x + x.y*y.y + x.z*y.z + x.w*y.w;
#pragma unroll
    for (int m = 32; m >= 1; m >>= 1) {
      skk += __shfl_xor(skk, m, 64);
      svv += __shfl_xor(svv, m, 64);
      skv += __shfl_xor(skv, m, 64);
    }
    float nk  = fmaxf(sqrtf(skk), 1e-8f);
    float nvv = fmaxf(sqrtf(svv), 1e-8f);
    if (lane == 0) posPart[row] = skv / (nk * nvv);
    float rk = 1.0f / nk;
    int w = __builtin_amdgcn_cvt_pk_fp8_f32(x.x * rk, x.y * rk, 0, false);
    w = __builtin_amdgcn_cvt_pk_fp8_f32(x.z * rk, x.w * rk, w, true);
    pkn[(size_t)row * 64 + lane] = (unsigned int)w;
  } else {
    int r2 = row - N;
    float4 x = nv[r2 * D4 + lane];
    float s = x.x*x.x + x.y*x.y + x.z*x.z + x.w*x.w;
#pragma unroll
    for (int m = 32; m >= 1; m >>= 1) s += __shfl_xor(s, m, 64);
    float rn = 1.0f / fmaxf(sqrtf(s), 1e-8f);
    int w = __builtin_amdgcn_cvt_pk_fp8_f32(x.x * rn, x.y * rn, 0, false);
    w = __builtin_amdgcn_cvt_pk_fp8_f32(x.z * rn, x.w * rn, w, true);
    nvn[(size_t)r2 * 64 + lane] = (unsigned int)w;
  }
}

// Fused fp8 GEMM + exp(sim/2) + row-sum + LAST-ARRIVER FINALIZE.
// R13 theory: R6 == R5 to 0.01us despite removing half the LDS traffic ->
// the gemm is NOT the ~33us my subtraction model claimed; the additive
// model's "rest" (~23-28us, from R1/R2's direct gemm measurements) hides
// ~15-20us of dispatch overhead. So this round removes dispatches, not
// gemm cycles: memset folded into normalize; finalize folded here as a
// G16 last-arriver tail (threadfence + per-panel atomic counter; the 8th
// cg-block of each panel finalizes its 256 rows with the BIT-IDENTICAL
// summation tree of the old finalize kernel). Gemm core = R6, untouched.
__global__ __launch_bounds__(512, 2) void gemm_lse_kernel(
    const unsigned char* __restrict__ gA, const unsigned char* __restrict__ gB,
    float* __restrict__ partial, const float* __restrict__ posPart,
    int* __restrict__ ctr, float* __restrict__ out, int N, float invN) {
  __shared__ unsigned char Bs[4][32768];  // per buf: [2 kb][128 rows][8 chunks]
  __shared__ int amLast;

  const int tid  = threadIdx.x;
  const int lane = tid & 63;
  const int wv   = tid >> 6;      // 0..7
  const int wm   = wv >> 1;       // 0..3 : 64-row strip of the 256-row panel
  const int wn   = wv & 1;        // 0..1 : 64-col half of the 128-col tile
  const int l15  = lane & 15, q = lane >> 4;
  const int cg    = blockIdx.x;   // 0..7  : 1024-col group (fixed per XCD)
  const int panel = blockIdx.y;   // 0..31 : 256-row panel
  const int row0  = panel * 256;
  const int colBase = cg * 1024;
  const float kLog2eHalf = 0.72134752044448170f;  // log2(e)/2
  const int kUnitScale = 0x7F7F7F7F;              // e8m0 127 = 2^0 per byte

  auto stageB = [&](int t) {
    const unsigned char* src = gB + (size_t)(colBase + t * 128) * 256;
    unsigned char* dst = &Bs[t & 3][0];
#pragma unroll
    for (int kb = 0; kb < 2; kb++)
#pragma unroll
      for (int i = 0; i < 2; i++) {
        int c  = i * 512 + tid;            // chunk within this kb-half
        int r  = c >> 3;                   // 0..127
        int sc = ((c & 7) ^ (r & 7)) << 4; // pre-swizzled global source col
        GLD_LDS16(src + (size_t)r * 256 + kb * 128 + sc,
                  dst + kb * 16384 + c * 16);
      }
  };

  // A fragments straight to registers, once (16 dwordx4 per thread).
  const unsigned char* aB = gA + (size_t)(row0 + wm * 64 + l15) * 256 + q * 32;
  i32x8 af[2][4];
#pragma unroll
  for (int kb = 0; kb < 2; kb++)
#pragma unroll
    for (int mi = 0; mi < 4; mi++)
      af[kb][mi] = *(const i32x8*)(aB + mi * 16 * 256 + kb * 128);
  __builtin_amdgcn_sched_barrier(0);   // pin: A loads issue before B stages

  stageB(0);
  stageB(1);
  stageB(2);
  __builtin_amdgcn_sched_barrier(0);

#pragma unroll
  for (int t = 0; t < 8; t++) {
    if      (t == 0) TILE_WAIT(7);
    else if (t == 1) TILE_WAIT(8);
    else if (t == 2) TILE_WAIT(9);
    else if (t == 3) TILE_WAIT(10);
    else if (t == 4) TILE_WAIT(10);
    else if (t == 5) TILE_WAIT(10);
    else if (t == 6) TILE_WAIT(6);
    else             TILE_WAIT(2);

    if (t < 5) {
      stageB(t + 3);
      __builtin_amdgcn_sched_barrier(0);
    }

    const unsigned char* bufB = &Bs[t & 3][0];
    f32x4 acc[4][4];
#pragma unroll
    for (int mi = 0; mi < 4; mi++)
#pragma unroll
      for (int ni = 0; ni < 4; ni++) acc[mi][ni] = (f32x4){0.f, 0.f, 0.f, 0.f};

#pragma unroll
    for (int kb = 0; kb < 2; kb++) {
      i32x8 bf[4];
#pragma unroll
      for (int ni = 0; ni < 4; ni++) {
        int r  = wn * 64 + ni * 16 + l15;           // 0..127
        int c0 = (q * 2)     ^ (r & 7);
        int c1 = (q * 2 + 1) ^ (r & 7);
        i32x4 lo = *(const i32x4*)(bufB + kb * 16384 + r * 128 + c0 * 16);
        i32x4 hi = *(const i32x4*)(bufB + kb * 16384 + r * 128 + c1 * 16);
        bf[ni] = (i32x8){lo.x, lo.y, lo.z, lo.w, hi.x, hi.y, hi.z, hi.w};
      }
#pragma unroll
      for (int mi = 0; mi < 4; mi++) {
        __builtin_amdgcn_s_setprio(1);
#pragma unroll
        for (int ni = 0; ni < 4; ni++)
          acc[mi][ni] = __builtin_amdgcn_mfma_scale_f32_16x16x128_f8f6f4(
              bf[ni], af[kb][mi], acc[mi][ni],    // SWAPPED: D[col][row]
              0, 0, 0, kUnitScale, 0, kUnitScale);
        __builtin_amdgcn_s_setprio(0);
      }
    }

    // epilogue (R4/R5-verified): row-sum in-register + 2 cross-q shuffles.
    float s0, s1, s2, s3;
#pragma unroll
    for (int mi = 0; mi < 4; mi++) {
      float v = 0.f;
#pragma unroll
      for (int ni = 0; ni < 4; ni++)
#pragma unroll
        for (int rr = 0; rr < 4; rr++)
          v += __builtin_amdgcn_exp2f(acc[mi][ni][rr] * kLog2eHalf);
      v += __shfl_xor(v, 16, 64);
      v += __shfl_xor(v, 32, 64);
      if (mi == 0) s0 = v; else if (mi == 1) s1 = v;
      else if (mi == 2) s2 = v; else s3 = v;
    }
    float o = q == 0 ? s0 : q == 1 ? s1 : q == 2 ? s2 : s3;
    int slab = cg * 16 + t * 2 + wn;                // 64-col slab, 0..127
    partial[(size_t)slab * N + row0 + wm * 64 + q * 16 + l15] = o;
    __builtin_amdgcn_sched_barrier(0);   // pin: store issues before next stage
  }

  // ---- fused finalize: last of the 8 cg-blocks for this panel ----
  // Release: own partial stores -> device scope, then count arrival.
  __threadfence();
  __syncthreads();
  if (tid == 0) amLast = (atomicAdd(&ctr[panel], 1) == 7) ? 1 : 0;
  __syncthreads();
  if (amLast) {
    __threadfence();   // acquire side: see the other 7 blocks' partials
    if (wv < 4) {
      int row = row0 + wv * 64 + lane;   // 4 waves x 64 consecutive rows
      const float* p = partial + row;
      // bit-identical to old finalize: 4 sequential groups of 32 slabs,
      // left-assoc combine, then the same 64-lane butterfly + atomicAdd.
      float g0 = 0.f, g1 = 0.f, g2 = 0.f, g3 = 0.f;
#pragma unroll 8
      for (int j = 0; j < 32; j++) g0 += p[(size_t)j * N];
#pragma unroll 8
      for (int j = 0; j < 32; j++) g1 += p[(size_t)(32 + j) * N];
#pragma unroll 8
      for (int j = 0; j < 32; j++) g2 += p[(size_t)(64 + j) * N];
#pragma unroll 8
      for (int j = 0; j < 32; j++) g3 += p[(size_t)(96 + j) * N];
      float tot = g0 + g1 + g2 + g3;
      float v = __builtin_amdgcn_logf(tot) * 0.69314718055994531f
                - 0.5f * posPart[row];
#pragma unroll
      for (int m = 32; m >= 1; m >>= 1) v += __shfl_xor(v, m, 64);
      if (lane == 0) atomicAdd(out, v * invN);
    }
  }
}

extern "C" void kernel_launch(void* const* d_in, const int* in_sizes, int n_in,
                              void* d_out, int out_size, void* d_ws, size_t ws_size,
                              hipStream_t stream) {
  const float* pk = (const float*)d_in[0];
  const float* pv = (const float*)d_in[1];
  const float* nv = (const float*)d_in[2];
  int N = in_sizes[0] / DIM;   // 8192
  int M = in_sizes[2] / DIM;   // 8192
  float* out = (float*)d_out;

  unsigned char* pkn = (unsigned char*)d_ws;                   // [N,256] fp8
  unsigned char* nvn = pkn + (size_t)N * DIM;                  // [M,256] fp8
  float* partial = (float*)(nvn + (size_t)M * DIM);            // [M/64][N] fp32
  float* posPart = partial + (size_t)(M / 64) * N;             // [N] fp32
  int*   ctr     = (int*)(posPart + N);                        // [32] counters

  // 2 dispatches total (was 4): memset folded into normalize, finalize
  // folded into gemm's last-arriver tail.
  normalize_kernel<<<(N + M) / 4, 256, 0, stream>>>(
      (const float4*)pk, (const float4*)pv, (const float4*)nv,
      (unsigned int*)pkn, (unsigned int*)nvn, posPart, ctr, out, N);

  // grid: x = col-group (M/1024 = 8), y = row panel (32).
  gemm_lse_kernel<<<dim3(M / 1024, N / 256), 512, 0, stream>>>(
      pkn, nvn, partial, posPart, ctr, out, N, 1.0f / (float)N);
}

// Round 8
// 113.952 us; speedup vs baseline: 1.2585x; 1.2585x over previous
//
#include <hip/hip_runtime.h>

typedef __attribute__((ext_vector_type(4))) float f32x4;
typedef __attribute__((ext_vector_type(4))) int   i32x4;
typedef __attribute__((ext_vector_type(8))) int   i32x8;

#define DIM 256
#define D4  64    // float4 per row

// One wave per row. Rows [0,N): exact fp32 pos_sim -> posPart[row] + normalized
// pk -> fp8 e4m3. Rows [N,N+M): normalized nv -> fp8. Block 0 zeroes `out`
// (replaces the hipMemsetAsync dispatch; stream order makes it visible to
// finalize). ctr/fence machinery from R7 reverted.
__global__ __launch_bounds__(256) void normalize_kernel(
    const float4* __restrict__ pk, const float4* __restrict__ pv,
    const float4* __restrict__ nv, unsigned int* __restrict__ pkn,
    unsigned int* __restrict__ nvn, float* __restrict__ posPart,
    float* __restrict__ out, int N) {
  if (blockIdx.x == 0 && threadIdx.x == 0) out[0] = 0.f;
  int row  = blockIdx.x * 4 + (threadIdx.x >> 6);
  int lane = threadIdx.x & 63;
  if (row < N) {
    float4 x = pk[row * D4 + lane];
    float4 y = pv[row * D4 + lane];
    float skk = x.x*x.x + x.y*x.y + x.z*x.z + x.w*x.w;
    float svv = y.x*y.x + y.y*y.y + y.z*y.z + y.w*y.w;
    float skv = x.x*y.x + x.y*y.y + x.z*y.z + x.w*y.w;
#pragma unroll
    for (int m = 32; m >= 1; m >>= 1) {
      skk += __shfl_xor(skk, m, 64);
      svv += __shfl_xor(svv, m, 64);
      skv += __shfl_xor(skv, m, 64);
    }
    float nk  = fmaxf(sqrtf(skk), 1e-8f);
    float nvv = fmaxf(sqrtf(svv), 1e-8f);
    if (lane == 0) posPart[row] = skv / (nk * nvv);
    float rk = 1.0f / nk;
    int w = __builtin_amdgcn_cvt_pk_fp8_f32(x.x * rk, x.y * rk, 0, false);
    w = __builtin_amdgcn_cvt_pk_fp8_f32(x.z * rk, x.w * rk, w, true);
    pkn[(size_t)row * 64 + lane] = (unsigned int)w;
  } else {
    int r2 = row - N;
    float4 x = nv[r2 * D4 + lane];
    float s = x.x*x.x + x.y*x.y + x.z*x.z + x.w*x.w;
#pragma unroll
    for (int m = 32; m >= 1; m >>= 1) s += __shfl_xor(s, m, 64);
    float rn = 1.0f / fmaxf(sqrtf(s), 1e-8f);
    int w = __builtin_amdgcn_cvt_pk_fp8_f32(x.x * rn, x.y * rn, 0, false);
    w = __builtin_amdgcn_cvt_pk_fp8_f32(x.z * rn, x.w * rn, w, true);
    nvn[(size_t)r2 * 64 + lane] = (unsigned int)w;
  }
}

// Fused fp8 GEMM (MX 16x16x128, unit scales = exact fp8) + exp(sim/2) + row-sum.
// R14: BARRIER-FREE, LDS-FREE. R7's direct gemm measurement (82-93us, MfmaUtil
// 7.6%, Occ 15%) + R6's neutrality show the R5/R6 structure idles on per-tile
// barrier lockstep at 1 block/CU: all 8 waves re-sync every ~2k cy; any
// straggler stalls the whole CU. The barrier only protected LDS B-buffers.
// With A resident in registers (2MB read once -- the thing R2 lacked), direct
// per-tile B fragment reads cost 128KB/block/tile -> 256MB L2 total (~8us BW,
// XCD-local since cg = linear-id % 8), so B staging buys nothing. Dropping LDS
// deletes every barrier and vmcnt: 8 waves free-run, MFMA/VMEM/epilogue-VALU
// of different waves overlap (m114), compiler pipelines across tiles.
// Fragment addressing = R2-verified direct form; swapped MFMA + in-register
// epilogue = R4/R5/R6-verified; accumulation order unchanged -> absmax 0.
__global__ __launch_bounds__(512, 2) void gemm_lse_kernel(
    const unsigned char* __restrict__ gA, const unsigned char* __restrict__ gB,
    float* __restrict__ partial, int N) {
  const int tid  = threadIdx.x;
  const int lane = tid & 63;
  const int wv   = tid >> 6;      // 0..7
  const int wm   = wv >> 1;       // 0..3 : 64-row strip of the 256-row panel
  const int wn   = wv & 1;        // 0..1 : 64-col half of the 128-col tile
  const int l15  = lane & 15, q = lane >> 4;
  const int cg    = blockIdx.x;   // 0..7  : 1024-col group (fixed per XCD)
  const int panel = blockIdx.y;   // 0..31 : 256-row panel
  const int row0  = panel * 256;
  const int colBase = cg * 1024;
  const float kLog2eHalf = 0.72134752044448170f;  // log2(e)/2
  const int kUnitScale = 0x7F7F7F7F;              // e8m0 127 = 2^0 per byte

  // A fragments straight to registers, once (16 dwordx4 per thread).
  // Row = row0 + wm*64 + mi*16 + l15; K-bytes kb*128 + q*32 .. +31.
  const unsigned char* aB = gA + (size_t)(row0 + wm * 64 + l15) * 256 + q * 32;
  i32x8 af[2][4];
#pragma unroll
  for (int kb = 0; kb < 2; kb++)
#pragma unroll
    for (int mi = 0; mi < 4; mi++)
      af[kb][mi] = *(const i32x8*)(aB + mi * 16 * 256 + kb * 128);

#pragma unroll
  for (int t = 0; t < 8; t++) {
    // B fragments direct from L2 (same bytes the LDS path delivered):
    // col = colBase + t*128 + wn*64 + ni*16 + l15, K-bytes kb*128 + q*32.
    const unsigned char* bT =
        gB + (size_t)(colBase + t * 128 + wn * 64 + l15) * 256 + q * 32;
    i32x8 bf[2][4];
#pragma unroll
    for (int kb = 0; kb < 2; kb++)
#pragma unroll
      for (int ni = 0; ni < 4; ni++)
        bf[kb][ni] = *(const i32x8*)(bT + ni * 16 * 256 + kb * 128);

    f32x4 acc[4][4];
#pragma unroll
    for (int mi = 0; mi < 4; mi++)
#pragma unroll
      for (int ni = 0; ni < 4; ni++) acc[mi][ni] = (f32x4){0.f, 0.f, 0.f, 0.f};

#pragma unroll
    for (int kb = 0; kb < 2; kb++)
#pragma unroll
      for (int mi = 0; mi < 4; mi++) {
        __builtin_amdgcn_s_setprio(1);
#pragma unroll
        for (int ni = 0; ni < 4; ni++)
          acc[mi][ni] = __builtin_amdgcn_mfma_scale_f32_16x16x128_f8f6f4(
              bf[kb][ni], af[kb][mi], acc[mi][ni],    // SWAPPED: D[col][row]
              0, 0, 0, kUnitScale, 0, kUnitScale);
        __builtin_amdgcn_s_setprio(0);
      }

    // epilogue (R4/R5-verified): lane l15 = pk-row within 16; regs span
    // nv-cols. Row-sum over the wave's 64 cols = in-register + 2 shuffles.
    float s0, s1, s2, s3;
#pragma unroll
    for (int mi = 0; mi < 4; mi++) {
      float v = 0.f;
#pragma unroll
      for (int ni = 0; ni < 4; ni++)
#pragma unroll
        for (int rr = 0; rr < 4; rr++)
          v += __builtin_amdgcn_exp2f(acc[mi][ni][rr] * kLog2eHalf);
      v += __shfl_xor(v, 16, 64);
      v += __shfl_xor(v, 32, 64);
      if (mi == 0) s0 = v; else if (mi == 1) s1 = v;
      else if (mi == 2) s2 = v; else s3 = v;
    }
    float o = q == 0 ? s0 : q == 1 ? s1 : q == 2 ? s2 : s3;
    int slab = cg * 16 + t * 2 + wn;                // 64-col slab, 0..127
    partial[(size_t)slab * N + row0 + wm * 64 + q * 16 + l15] = o;
  }
}

// out = mean(ln(sum_j partial[j][row])) - 0.5*mean(posPart). R5/R6 version,
// reverted to its own dispatch (partial is [M/64=128][N]).
__global__ __launch_bounds__(256) void finalize_kernel(
    const float* __restrict__ partial, const float* __restrict__ posPart,
    float* __restrict__ out, int N, int slabsPerGroup, float invN) {
  __shared__ float red[4][64];
  int t  = threadIdx.x;
  int rl = t & 63, g = t >> 6;
  int row = blockIdx.x * 64 + rl;
  const float* p = partial + (size_t)(g * slabsPerGroup) * N + row;
  float s = 0.f;
#pragma unroll 8
  for (int j = 0; j < slabsPerGroup; j++) s += p[(size_t)j * N];
  red[g][rl] = s;
  __syncthreads();
  if (t < 64) {
    float tot = red[0][rl] + red[1][rl] + red[2][rl] + red[3][rl];
    float v = __builtin_amdgcn_logf(tot) * 0.69314718055994531f
              - 0.5f * posPart[row];
#pragma unroll
    for (int m = 32; m >= 1; m >>= 1) v += __shfl_xor(v, m, 64);
    if (rl == 0) atomicAdd(out, v * invN);
  }
}

extern "C" void kernel_launch(void* const* d_in, const int* in_sizes, int n_in,
                              void* d_out, int out_size, void* d_ws, size_t ws_size,
                              hipStream_t stream) {
  const float* pk = (const float*)d_in[0];
  const float* pv = (const float*)d_in[1];
  const float* nv = (const float*)d_in[2];
  int N = in_sizes[0] / DIM;   // 8192
  int M = in_sizes[2] / DIM;   // 8192
  float* out = (float*)d_out;

  unsigned char* pkn = (unsigned char*)d_ws;                   // [N,256] fp8
  unsigned char* nvn = pkn + (size_t)N * DIM;                  // [M,256] fp8
  float* partial = (float*)(nvn + (size_t)M * DIM);            // [M/64][N] fp32
  float* posPart = partial + (size_t)(M / 64) * N;             // [N] fp32

  // 3 dispatches: memset stays folded into normalize (sound; R7's failure
  // was the per-block device fence, not the fold).
  normalize_kernel<<<(N + M) / 4, 256, 0, stream>>>(
      (const float4*)pk, (const float4*)pv, (const float4*)nv,
      (unsigned int*)pkn, (unsigned int*)nvn, posPart, out, N);

  // grid: x = col-group (M/1024 = 8, one per XCD slot), y = row panel (32).
  gemm_lse_kernel<<<dim3(M / 1024, N / 256), 512, 0, stream>>>(
      pkn, nvn, partial, N);

  finalize_kernel<<<N / 64, 256, 0, stream>>>(
      partial, posPart, out, N, (M / 64) / 4, 1.0f / (float)N);
}

// Round 9
// 98.891 us; speedup vs baseline: 1.4501x; 1.1523x over previous
//
#include <hip/hip_runtime.h>

typedef __attribute__((ext_vector_type(4))) float f32x4;
typedef __attribute__((ext_vector_type(4))) int   i32x4;
typedef __attribute__((ext_vector_type(8))) int   i32x8;

#define DIM 256
#define D4  64    // float4 per row

// async global->LDS, 16B per lane; LDS dest = wave-uniform base + lane*16.
#define GLD_LDS16(g, l) __builtin_amdgcn_global_load_lds(                      \
    (const __attribute__((address_space(1))) void*)(g),                        \
    (__attribute__((address_space(3))) void*)(l), 16, 0, 0)

// wait for all but the newest N VMEM ops, then barrier (counted prefetch).
#define TILE_WAIT(N) asm volatile("s_waitcnt vmcnt(" #N ")\n\ts_barrier" ::: "memory")

// One wave per row. Rows [0,N): exact fp32 pos_sim -> posPart[row] + normalized
// pk -> fp8 e4m3. Rows [N,N+M): normalized nv -> fp8. Block 0 zeroes `out`
// (replaces the hipMemsetAsync dispatch; stream order -> visible to finalize).
__global__ __launch_bounds__(256) void normalize_kernel(
    const float4* __restrict__ pk, const float4* __restrict__ pv,
    const float4* __restrict__ nv, unsigned int* __restrict__ pkn,
    unsigned int* __restrict__ nvn, float* __restrict__ posPart,
    float* __restrict__ out, int N) {
  if (blockIdx.x == 0 && threadIdx.x == 0) out[0] = 0.f;
  int row  = blockIdx.x * 4 + (threadIdx.x >> 6);
  int lane = threadIdx.x & 63;
  if (row < N) {
    float4 x = pk[row * D4 + lane];
    float4 y = pv[row * D4 + lane];
    float skk = x.x*x.x + x.y*x.y + x.z*x.z + x.w*x.w;
    float svv = y.x*y.x + y.y*y.y + y.z*y.z + y.w*y.w;
    float skv = x.x*y.x + x.y*y.y + x.z*y.z + x.w*y.w;
#pragma unroll
    for (int m = 32; m >= 1; m >>= 1) {
      skk += __shfl_xor(skk, m, 64);
      svv += __shfl_xor(svv, m, 64);
      skv += __shfl_xor(skv, m, 64);
    }
    float nk  = fmaxf(sqrtf(skk), 1e-8f);
    float nvv = fmaxf(sqrtf(svv), 1e-8f);
    if (lane == 0) posPart[row] = skv / (nk * nvv);
    float rk = 1.0f / nk;
    int w = __builtin_amdgcn_cvt_pk_fp8_f32(x.x * rk, x.y * rk, 0, false);
    w = __builtin_amdgcn_cvt_pk_fp8_f32(x.z * rk, x.w * rk, w, true);
    pkn[(size_t)row * 64 + lane] = (unsigned int)w;
  } else {
    int r2 = row - N;
    float4 x = nv[r2 * D4 + lane];
    float s = x.x*x.x + x.y*x.y + x.z*x.z + x.w*x.w;
#pragma unroll
    for (int m = 32; m >= 1; m >>= 1) s += __shfl_xor(s, m, 64);
    float rn = 1.0f / fmaxf(sqrtf(s), 1e-8f);
    int w = __builtin_amdgcn_cvt_pk_fp8_f32(x.x * rn, x.y * rn, 0, false);
    w = __builtin_amdgcn_cvt_pk_fp8_f32(x.z * rn, x.w * rn, w, true);
    nvn[(size_t)r2 * 64 + lane] = (unsigned int)w;
  }
}

// Fused fp8 GEMM (MX 16x16x128, unit scales = exact fp8) + exp(sim/2) + row-sum.
// R15 = R6 macro-structure (persistent 256-row panel, A-in-regs, 4-deep LDS B,
// counted vmcnt -- best total, 101us) + INTRA-WAVE INTERLEAVE: R8's barrier-
// free probe showed 72% idle cycles with MfmaUtil 12% -> the per-wave serial
// chain {MFMA burst -> epilogue chain} leaves the matrix pipe empty during
// the ~700cy epilogue (exp2+reduce) at only 2 waves/SIMD. Calibration: this
// fused kernel is attention-class; m214's plain-HIP plateau ~900 TF == our
// ~860 TF. Its proven intra-wave lever (sm-split, +5%): interleave epilogue
// slices BETWEEN MFMA clusters. mi-outer nesting: per mi, 8 MFMAs (kb0,kb1)
// then that mi's epilogue slice -> overlaps mi+1's MFMAs on different pipes.
// acc live drops 64->16 AGPR. Per-(mi,ni) accumulation order still kb0->kb1;
// epilogue sum order unchanged -> bit-identical (absmax 0). setprio removed
// (m190: null/neg on barrier-synced GEMM). Staging/vmcnt identical to R6.
__global__ __launch_bounds__(512, 2) void gemm_lse_kernel(
    const unsigned char* __restrict__ gA, const unsigned char* __restrict__ gB,
    float* __restrict__ partial, int N) {
  __shared__ unsigned char Bs[4][32768];  // per buf: [2 kb][128 rows][8 chunks]

  const int tid  = threadIdx.x;
  const int lane = tid & 63;
  const int wv   = tid >> 6;      // 0..7
  const int wm   = wv >> 1;       // 0..3 : 64-row strip of the 256-row panel
  const int wn   = wv & 1;        // 0..1 : 64-col half of the 128-col tile
  const int l15  = lane & 15, q = lane >> 4;
  const int cg    = blockIdx.x;   // 0..7  : 1024-col group (fixed per XCD)
  const int panel = blockIdx.y;   // 0..31 : 256-row panel
  const int row0  = panel * 256;
  const int colBase = cg * 1024;
  const float kLog2eHalf = 0.72134752044448170f;  // log2(e)/2
  const int kUnitScale = 0x7F7F7F7F;              // e8m0 127 = 2^0 per byte

  auto stageB = [&](int t) {
    const unsigned char* src = gB + (size_t)(colBase + t * 128) * 256;
    unsigned char* dst = &Bs[t & 3][0];
#pragma unroll
    for (int kb = 0; kb < 2; kb++)
#pragma unroll
      for (int i = 0; i < 2; i++) {
        int c  = i * 512 + tid;            // chunk within this kb-half
        int r  = c >> 3;                   // 0..127
        int sc = ((c & 7) ^ (r & 7)) << 4; // pre-swizzled global source col
        GLD_LDS16(src + (size_t)r * 256 + kb * 128 + sc,
                  dst + kb * 16384 + c * 16);
      }
  };

  // A fragments straight to registers, once (16 dwordx4 per thread).
  const unsigned char* aB = gA + (size_t)(row0 + wm * 64 + l15) * 256 + q * 32;
  i32x8 af[2][4];
#pragma unroll
  for (int kb = 0; kb < 2; kb++)
#pragma unroll
    for (int mi = 0; mi < 4; mi++)
      af[kb][mi] = *(const i32x8*)(aB + mi * 16 * 256 + kb * 128);
  __builtin_amdgcn_sched_barrier(0);   // pin: A loads issue before B stages

  stageB(0);
  stageB(1);
  stageB(2);
  __builtin_amdgcn_sched_barrier(0);

#pragma unroll
  for (int t = 0; t < 8; t++) {
    if      (t == 0) TILE_WAIT(7);
    else if (t == 1) TILE_WAIT(8);
    else if (t == 2) TILE_WAIT(9);
    else if (t == 3) TILE_WAIT(10);
    else if (t == 4) TILE_WAIT(10);
    else if (t == 5) TILE_WAIT(10);
    else if (t == 6) TILE_WAIT(6);
    else             TILE_WAIT(2);

    if (t < 5) {
      stageB(t + 3);
      __builtin_amdgcn_sched_barrier(0);
    }

    const unsigned char* bufB = &Bs[t & 3][0];

    // All B fragments for this tile (both kb halves): 16 ds_read_b128.
    i32x8 bf[2][4];
#pragma unroll
    for (int kb = 0; kb < 2; kb++)
#pragma unroll
      for (int ni = 0; ni < 4; ni++) {
        int r  = wn * 64 + ni * 16 + l15;           // 0..127
        int c0 = (q * 2)     ^ (r & 7);
        int c1 = (q * 2 + 1) ^ (r & 7);
        i32x4 lo = *(const i32x4*)(bufB + kb * 16384 + r * 128 + c0 * 16);
        i32x4 hi = *(const i32x4*)(bufB + kb * 16384 + r * 128 + c1 * 16);
        bf[kb][ni] = (i32x8){lo.x, lo.y, lo.z, lo.w, hi.x, hi.y, hi.z, hi.w};
      }

    // mi-outer: 8 MFMAs for mi, then mi's epilogue slice -- the slice's
    // exp2/adds/shuffles (trans/VALU/DS pipes) overlap mi+1's MFMAs.
    float s0, s1, s2, s3;
#pragma unroll
    for (int mi = 0; mi < 4; mi++) {
      f32x4 acc[4];
#pragma unroll
      for (int ni = 0; ni < 4; ni++) acc[ni] = (f32x4){0.f, 0.f, 0.f, 0.f};
#pragma unroll
      for (int kb = 0; kb < 2; kb++)
#pragma unroll
        for (int ni = 0; ni < 4; ni++)
          acc[ni] = __builtin_amdgcn_mfma_scale_f32_16x16x128_f8f6f4(
              bf[kb][ni], af[kb][mi], acc[ni],      // SWAPPED: D[col][row]
              0, 0, 0, kUnitScale, 0, kUnitScale);
      float v = 0.f;
#pragma unroll
      for (int ni = 0; ni < 4; ni++)
#pragma unroll
        for (int rr = 0; rr < 4; rr++)
          v += __builtin_amdgcn_exp2f(acc[ni][rr] * kLog2eHalf);
      v += __shfl_xor(v, 16, 64);
      v += __shfl_xor(v, 32, 64);
      if (mi == 0) s0 = v; else if (mi == 1) s1 = v;
      else if (mi == 2) s2 = v; else s3 = v;
    }
    float o = q == 0 ? s0 : q == 1 ? s1 : q == 2 ? s2 : s3;
    int slab = cg * 16 + t * 2 + wn;                // 64-col slab, 0..127
    partial[(size_t)slab * N + row0 + wm * 64 + q * 16 + l15] = o;
    __builtin_amdgcn_sched_barrier(0);   // pin: store issues before next stage
  }
}

// out = mean(ln(sum_j partial[j][row])) - 0.5*mean(posPart). UNCHANGED
// (partial is [M/64=128][N]).
__global__ __launch_bounds__(256) void finalize_kernel(
    const float* __restrict__ partial, const float* __restrict__ posPart,
    float* __restrict__ out, int N, int slabsPerGroup, float invN) {
  __shared__ float red[4][64];
  int t  = threadIdx.x;
  int rl = t & 63, g = t >> 6;
  int row = blockIdx.x * 64 + rl;
  const float* p = partial + (size_t)(g * slabsPerGroup) * N + row;
  float s = 0.f;
#pragma unroll 8
  for (int j = 0; j < slabsPerGroup; j++) s += p[(size_t)j * N];
  red[g][rl] = s;
  __syncthreads();
  if (t < 64) {
    float tot = red[0][rl] + red[1][rl] + red[2][rl] + red[3][rl];
    float v = __builtin_amdgcn_logf(tot) * 0.69314718055994531f
              - 0.5f * posPart[row];
#pragma unroll
    for (int m = 32; m >= 1; m >>= 1) v += __shfl_xor(v, m, 64);
    if (rl == 0) atomicAdd(out, v * invN);
  }
}

extern "C" void kernel_launch(void* const* d_in, const int* in_sizes, int n_in,
                              void* d_out, int out_size, void* d_ws, size_t ws_size,
                              hipStream_t stream) {
  const float* pk = (const float*)d_in[0];
  const float* pv = (const float*)d_in[1];
  const float* nv = (const float*)d_in[2];
  int N = in_sizes[0] / DIM;   // 8192
  int M = in_sizes[2] / DIM;   // 8192
  float* out = (float*)d_out;

  unsigned char* pkn = (unsigned char*)d_ws;                   // [N,256] fp8
  unsigned char* nvn = pkn + (size_t)N * DIM;                  // [M,256] fp8
  float* partial = (float*)(nvn + (size_t)M * DIM);            // [M/64][N] fp32
  float* posPart = partial + (size_t)(M / 64) * N;             // [N] fp32

  normalize_kernel<<<(N + M) / 4, 256, 0, stream>>>(
      (const float4*)pk, (const float4*)pv, (const float4*)nv,
      (unsigned int*)pkn, (unsigned int*)nvn, posPart, out, N);

  // grid: x = col-group (M/1024 = 8, one per XCD slot), y = row panel (32).
  gemm_lse_kernel<<<dim3(M / 1024, N / 256), 512, 0, stream>>>(
      pkn, nvn, partial, N);

  finalize_kernel<<<N / 64, 256, 0, stream>>>(
      partial, posPart, out, N, (M / 64) / 4, 1.0f / (float)N);
}